// Round 3
// baseline (344.241 us; speedup 1.0000x reference)
//
#include <hip/hip_runtime.h>
#include <math.h>

#define NEGINF (-INFINITY)
#define AGENT __HIP_MEMORY_SCOPE_AGENT

template <int M>
__device__ __forceinline__ float qbcast(float v) {
    // DPP quad_perm broadcast of lane M within each 4-lane quad (VALU, no LDS)
    return __int_as_float(
        __builtin_amdgcn_update_dpp(0, __float_as_int(v), M * 0x55, 0xF, 0xF, true));
}
__device__ __forceinline__ float fsigmoid(float z) { return 1.f / (1.f + __expf(-z)); }
__device__ __forceinline__ float ftanh(float z) {
    z = fminf(fmaxf(z, -20.f), 20.f);
    float e = __expf(2.f * z);
    return (e - 1.f) / (e + 1.f);
}

// Fused producer-consumer kernel.
// Block 0: consumer (LSTM). Blocks 1..256: producers, 8 images each, s-major rounds.
__global__ __launch_bounds__(256) void fused_kernel(
    const float* __restrict__ frames, const float* __restrict__ Wf,
    const float* __restrict__ bf, const float* __restrict__ We,
    const float* __restrict__ be, const float* __restrict__ Wih,
    const float* __restrict__ Whh, const float* __restrict__ bih,
    const float* __restrict__ bhh, const float* __restrict__ Wp,
    const float* __restrict__ bp, float* __restrict__ out_pooled,
    float* __restrict__ out_fc, float* __restrict__ prog,
    float* __restrict__ fprog, float* __restrict__ emb,
    float* __restrict__ femb, int* __restrict__ cnt) {
    int tid = threadIdx.x;

    if (blockIdx.x > 0) {
        // ---------------- producer ----------------
        int pid = blockIdx.x - 1;  // 0..255
        __shared__ float sw[4][4];
        __shared__ float sq[3][4];
        __shared__ float sp[15];
        __shared__ float sfc[15];
        for (int r = 0; r < 8; ++r) {
            int nidx = r * 256 + pid;          // s-major image index
            int s = nidx >> 4, b = nidx & 15;  // round r covers s in [16r, 16r+16)
            int n = b * 128 + s;
            const float4* __restrict__ base =
                reinterpret_cast<const float4*>(frames) + (size_t)n * 37632;
            for (int c = 0; c < 3; ++c) {
                const float4* __restrict__ pb = base + c * 12544;  // 224*56 float4
                float tl = NEGINF, tr = NEGINF, bl = NEGINF, br = NEGINF;
#pragma unroll 7
                for (int it = 0; it < 49; ++it) {
                    int i2 = (it << 8) + tid;  // 0..12543
                    float4 f = pb[i2];
                    float m = fmaxf(fmaxf(f.x, f.y), fmaxf(f.z, f.w));
                    int row = i2 / 56;
                    int c4 = i2 - row * 56;
                    bool top = row < 112;
                    bool left = c4 < 28;  // float4 never crosses the 28-boundary
                    float mt = top ? m : NEGINF;
                    float mb = top ? NEGINF : m;
                    tl = fmaxf(tl, left ? mt : NEGINF);
                    tr = fmaxf(tr, left ? NEGINF : mt);
                    bl = fmaxf(bl, left ? mb : NEGINF);
                    br = fmaxf(br, left ? NEGINF : mb);
                }
#pragma unroll
                for (int m = 32; m >= 1; m >>= 1) {
                    tl = fmaxf(tl, __shfl_xor(tl, m, 64));
                    tr = fmaxf(tr, __shfl_xor(tr, m, 64));
                    bl = fmaxf(bl, __shfl_xor(bl, m, 64));
                    br = fmaxf(br, __shfl_xor(br, m, 64));
                }
                int w = tid >> 6;
                if ((tid & 63) == 0) { sw[w][0] = tl; sw[w][1] = tr; sw[w][2] = bl; sw[w][3] = br; }
                __syncthreads();
                if (tid < 4)
                    sq[c][tid] = fmaxf(fmaxf(sw[0][tid], sw[1][tid]),
                                       fmaxf(sw[2][tid], sw[3][tid]));
                __syncthreads();
            }
            if (tid == 0) {
#pragma unroll
                for (int c = 0; c < 3; ++c) {
                    float a = sq[c][0], bq = sq[c][1], cq = sq[c][2], d = sq[c][3];
                    sp[c * 4 + 0] = a; sp[c * 4 + 1] = bq;
                    sp[c * 4 + 2] = cq; sp[c * 4 + 3] = d;
                    sp[12 + c] = fmaxf(fmaxf(a, bq), fmaxf(cq, d));
                }
            }
            __syncthreads();
            if (tid < 15) {
                float a = bf[tid];
#pragma unroll
                for (int kk = 0; kk < 15; ++kk) a += sp[kk] * Wf[tid * 15 + kk];
                sfc[tid] = a;
                out_pooled[n * 15 + tid] = sp[tid];
                out_fc[n * 15 + tid] = a;
            }
            __syncthreads();
            if (tid < 8) {
                float a = be[tid], a2 = be[tid];
#pragma unroll
                for (int kk = 0; kk < 15; ++kk) {
                    a += sp[kk] * We[tid * 15 + kk];
                    a2 += sfc[kk] * We[tid * 15 + kk];
                }
                __hip_atomic_store(&emb[n * 8 + tid], a, __ATOMIC_RELAXED, AGENT);
                __hip_atomic_store(&femb[n * 8 + tid], a2, __ATOMIC_RELAXED, AGENT);
            }
            __syncthreads();
            if (tid == 0)
                __hip_atomic_fetch_add(&cnt[s], 1, __ATOMIC_RELEASE, AGENT);
            __syncthreads();
        }
        return;
    }

    // ---------------- consumer: double-cell LSTM, one wave ----------------
    if (tid >= 64) return;
    int b = tid >> 2, k = tid & 3;
    float wih[4][8], whh[4][4], bsum[4];
#pragma unroll
    for (int g = 0; g < 4; g++) {
        int row = g * 4 + k;
#pragma unroll
        for (int m = 0; m < 8; m++) wih[g][m] = Wih[row * 8 + m];
#pragma unroll
        for (int m = 0; m < 4; m++) whh[g][m] = Whh[row * 4 + m];
        bsum[g] = bih[row] + bhh[row];
    }
    float wpv[4];
#pragma unroll
    for (int m = 0; m < 4; m++) wpv[m] = Wp[m];
    float bpv = bp[0];

    float h0 = 0.f, h1r = 0.f, h2r = 0.f, h3r = 0.f;
    float ck = 0.f;

    for (int s = 0; s < 128; ++s) {
        // wait for all 16 batches' embeddings for this step
        while (__hip_atomic_load(&cnt[s], __ATOMIC_ACQUIRE, AGENT) < 16) {
            __builtin_amdgcn_s_sleep(1);
        }
        float* xe = emb + (size_t)(b * 128 + s) * 8;
        float* xf = femb + (size_t)(b * 128 + s) * 8;
        float x1[8], x2[8];
#pragma unroll
        for (int m = 0; m < 8; m++) x1[m] = __hip_atomic_load(&xe[m], __ATOMIC_RELAXED, AGENT);
#pragma unroll
        for (int m = 0; m < 8; m++) x2[m] = __hip_atomic_load(&xf[m], __ATOMIC_RELAXED, AGENT);

        float xd1[4], xd2[4];
#pragma unroll
        for (int g = 0; g < 4; g++) {
            float a = bsum[g], a2 = bsum[g];
#pragma unroll
            for (int m = 0; m < 8; m++) {
                a += x1[m] * wih[g][m];
                a2 += x2[m] * wih[g][m];
            }
            xd1[g] = a;
            xd2[g] = a2;
        }

        // ---- cell 1 ----
        float g0 = xd1[0] + h0 * whh[0][0] + h1r * whh[0][1] + h2r * whh[0][2] + h3r * whh[0][3];
        float g1 = xd1[1] + h0 * whh[1][0] + h1r * whh[1][1] + h2r * whh[1][2] + h3r * whh[1][3];
        float g2 = xd1[2] + h0 * whh[2][0] + h1r * whh[2][1] + h2r * whh[2][2] + h3r * whh[2][3];
        float g3 = xd1[3] + h0 * whh[3][0] + h1r * whh[3][1] + h2r * whh[3][2] + h3r * whh[3][3];
        float c1 = fsigmoid(g1) * ck + fsigmoid(g0) * ftanh(g2);
        float hk1 = fsigmoid(g3) * ftanh(c1);
        float b0 = qbcast<0>(hk1), b1 = qbcast<1>(hk1), b2 = qbcast<2>(hk1), b3 = qbcast<3>(hk1);
        float z = bpv + b0 * wpv[0] + b1 * wpv[1] + b2 * wpv[2] + b3 * wpv[3];
        if (k == 0) prog[b * 128 + s] = fsigmoid(z);

        // ---- cell 2 (from h1, c1; its c is discarded) ----
        float e0 = xd2[0] + b0 * whh[0][0] + b1 * whh[0][1] + b2 * whh[0][2] + b3 * whh[0][3];
        float e1 = xd2[1] + b0 * whh[1][0] + b1 * whh[1][1] + b2 * whh[1][2] + b3 * whh[1][3];
        float e2 = xd2[2] + b0 * whh[2][0] + b1 * whh[2][1] + b2 * whh[2][2] + b3 * whh[2][3];
        float e3 = xd2[3] + b0 * whh[3][0] + b1 * whh[3][1] + b2 * whh[3][2] + b3 * whh[3][3];
        float c2v = fsigmoid(e1) * c1 + fsigmoid(e0) * ftanh(e2);
        float hk2 = fsigmoid(e3) * ftanh(c2v);
        float d0 = qbcast<0>(hk2), d1 = qbcast<1>(hk2), d2 = qbcast<2>(hk2), d3 = qbcast<3>(hk2);
        float z2 = bpv + d0 * wpv[0] + d1 * wpv[1] + d2 * wpv[2] + d3 * wpv[3];
        if (k == 0) fprog[b * 128 + s] = fsigmoid(z2);

        // carry = (h1, c1)
        h0 = b0; h1r = b1; h2r = b2; h3r = b3; ck = c1;
    }
}

extern "C" void kernel_launch(void* const* d_in, const int* in_sizes, int n_in,
                              void* d_out, int out_size, void* d_ws, size_t ws_size,
                              hipStream_t stream) {
    const float* frames = (const float*)d_in[0];
    const float* Wf     = (const float*)d_in[1];
    const float* bf     = (const float*)d_in[2];
    const float* We     = (const float*)d_in[3];
    const float* be     = (const float*)d_in[4];
    const float* Wih    = (const float*)d_in[5];
    const float* Whh    = (const float*)d_in[6];
    const float* bih    = (const float*)d_in[7];
    const float* bhh    = (const float*)d_in[8];
    const float* Wp     = (const float*)d_in[9];
    const float* bp     = (const float*)d_in[10];

    float* out = (float*)d_out;
    float* out_prog   = out;                  // (16,128)
    float* out_fprog  = out + 2048;           // (16,128)
    float* out_pooled = out + 4096;           // (16,128,15)
    float* out_fc     = out + 4096 + 30720;   // (16,128,15)

    char* ws = (char*)d_ws;
    int*   cnt  = (int*)ws;                     // 128 ints
    float* emb  = (float*)(ws + 512);           // 2048*8 floats
    float* femb = (float*)(ws + 512 + 65536);   // 2048*8 floats

    hipMemsetAsync(cnt, 0, 128 * sizeof(int), stream);
    fused_kernel<<<257, 256, 0, stream>>>(frames, Wf, bf, We, be, Wih, Whh, bih,
                                          bhh, Wp, bp, out_pooled, out_fc,
                                          out_prog, out_fprog, emb, femb, cnt);
}

// Round 5
// 280.030 us; speedup vs baseline: 1.2293x; 1.2293x over previous
//
#include <hip/hip_runtime.h>
#include <math.h>

#define NEGINF (-INFINITY)

typedef float fvec4 __attribute__((ext_vector_type(4)));

// ---------------- Kernel 1: SPP quadrant maxes ----------------
// frames: (2048, 3, 224, 224) fp32. One block per image-channel plane (6144 blocks).
// Active threads tid<224 map to (rowgroup=tid/56, col4=tid%56); iteration r reads
// the float4 at r*224+tid (contiguous 1KB/wave, zero per-iter index math).
// Top/bottom = two uniform loops; left/right resolved once in the masked reduce.
__global__ __launch_bounds__(256, 8) void spp_kernel(const float* __restrict__ frames,
                                                     float* __restrict__ quad) {
    int cimg = blockIdx.x;  // 0..6143
    int tid = threadIdx.x;
    const fvec4* __restrict__ base =
        reinterpret_cast<const fvec4*>(frames) + (size_t)cimg * 12544;  // 224*56 float4
    bool active = tid < 224;
    const fvec4* __restrict__ p = base + tid;
    float aT = NEGINF, aB = NEGINF;
#pragma unroll 7
    for (int r = 0; r < 28; ++r) {
        if (active) {
            fvec4 f = __builtin_nontemporal_load(&p[r * 224]);
            aT = fmaxf(aT, fmaxf(fmaxf(f.x, f.y), fmaxf(f.z, f.w)));
        }
    }
#pragma unroll 7
    for (int r = 28; r < 56; ++r) {
        if (active) {
            fvec4 f = __builtin_nontemporal_load(&p[r * 224]);
            aB = fmaxf(aB, fmaxf(fmaxf(f.x, f.y), fmaxf(f.z, f.w)));
        }
    }
    int cc = tid % 56;
    bool left  = active && (cc < 28);
    bool right = active && (cc >= 28);
    float tl = left ? aT : NEGINF;
    float tr = right ? aT : NEGINF;
    float bl = left ? aB : NEGINF;
    float br = right ? aB : NEGINF;
#pragma unroll
    for (int m = 32; m >= 1; m >>= 1) {
        tl = fmaxf(tl, __shfl_xor(tl, m, 64));
        tr = fmaxf(tr, __shfl_xor(tr, m, 64));
        bl = fmaxf(bl, __shfl_xor(bl, m, 64));
        br = fmaxf(br, __shfl_xor(br, m, 64));
    }
    __shared__ float s[4][4];
    int w = tid >> 6;
    if ((tid & 63) == 0) { s[w][0] = tl; s[w][1] = tr; s[w][2] = bl; s[w][3] = br; }
    __syncthreads();
    if (tid < 4) {
        float r = fmaxf(fmaxf(s[0][tid], s[1][tid]), fmaxf(s[2][tid], s[3][tid]));
        quad[cimg * 4 + tid] = r;
    }
}

// ---------------- Kernel 2: fused prep + LSTM (unchanged from round 2) ----------------
#define BSTRIDE 1036  // floats per batch in LDS: 128*8 + 12 pad

template <int M>
__device__ __forceinline__ float qbcast(float v) {
    return __int_as_float(
        __builtin_amdgcn_update_dpp(0, __float_as_int(v), M * 0x55, 0xF, 0xF, true));
}

__device__ __forceinline__ float fsigmoid(float z) { return 1.f / (1.f + __expf(-z)); }
__device__ __forceinline__ float ftanh(float z) {
    z = fminf(fmaxf(z, -20.f), 20.f);
    float e = __expf(2.f * z);
    return (e - 1.f) / (e + 1.f);
}

__device__ __forceinline__ float dot8(const float4& a, const float4& b,
                                      const float* __restrict__ w) {
    return a.x * w[0] + a.y * w[1] + a.z * w[2] + a.w * w[3] +
           b.x * w[4] + b.y * w[5] + b.z * w[6] + b.w * w[7];
}

__global__ __launch_bounds__(512, 1) void prep_lstm_kernel(
    const float* __restrict__ quad, const float* __restrict__ Wf,
    const float* __restrict__ bf, const float* __restrict__ We,
    const float* __restrict__ be, const float* __restrict__ Wih,
    const float* __restrict__ Whh, const float* __restrict__ bih,
    const float* __restrict__ bhh, const float* __restrict__ Wp,
    const float* __restrict__ bp, float* __restrict__ out_pooled,
    float* __restrict__ out_fc, float* __restrict__ prog,
    float* __restrict__ fprog) {
    extern __shared__ float lds[];
    float* lemb  = lds;                  // [16][BSTRIDE]
    float* lfemb = lds + 16 * BSTRIDE;   // [16][BSTRIDE]
    int tid = threadIdx.x;

    // ---- Phase 1: pooled / forecast / embeddings ----
    for (int n = tid; n < 2048; n += 512) {
        float p[15];
        float4 q0 = *(const float4*)(quad + n * 12);
        float4 q1 = *(const float4*)(quad + n * 12 + 4);
        float4 q2 = *(const float4*)(quad + n * 12 + 8);
        p[0] = q0.x; p[1] = q0.y; p[2] = q0.z; p[3] = q0.w;
        p[4] = q1.x; p[5] = q1.y; p[6] = q1.z; p[7] = q1.w;
        p[8] = q2.x; p[9] = q2.y; p[10] = q2.z; p[11] = q2.w;
#pragma unroll
        for (int c = 0; c < 3; c++)
            p[12 + c] = fmaxf(fmaxf(p[c * 4 + 0], p[c * 4 + 1]),
                              fmaxf(p[c * 4 + 2], p[c * 4 + 3]));
#pragma unroll
        for (int j = 0; j < 15; j++) out_pooled[n * 15 + j] = p[j];
        float fc[15];
#pragma unroll
        for (int j = 0; j < 15; j++) {
            float a = bf[j];
#pragma unroll
            for (int kk = 0; kk < 15; kk++) a += p[kk] * Wf[j * 15 + kk];
            fc[j] = a;
            out_fc[n * 15 + j] = a;
        }
        int b = n >> 7, sidx = n & 127;
        float* le = lemb  + b * BSTRIDE + sidx * 8;
        float* lf = lfemb + b * BSTRIDE + sidx * 8;
#pragma unroll
        for (int j = 0; j < 8; j++) {
            float a = be[j], a2 = be[j];
#pragma unroll
            for (int kk = 0; kk < 15; kk++) {
                a  += p[kk]  * We[j * 15 + kk];
                a2 += fc[kk] * We[j * 15 + kk];
            }
            le[j] = a;
            lf[j] = a2;
        }
    }
    __syncthreads();

    // ---- Phase 2: double-cell LSTM, single wave (16 batches x 4 hidden lanes) ----
    if (tid >= 64) return;
    int b = tid >> 2, k = tid & 3;
    float wih[4][8], whh[4][4], bsum[4];
#pragma unroll
    for (int g = 0; g < 4; g++) {
        int row = g * 4 + k;
#pragma unroll
        for (int m = 0; m < 8; m++) wih[g][m] = Wih[row * 8 + m];
#pragma unroll
        for (int m = 0; m < 4; m++) whh[g][m] = Whh[row * 4 + m];
        bsum[g] = bih[row] + bhh[row];
    }
    float wpv[4];
#pragma unroll
    for (int m = 0; m < 4; m++) wpv[m] = Wp[m];
    float bpv = bp[0];

    const float* xe = lemb  + b * BSTRIDE;
    const float* xf = lfemb + b * BSTRIDE;

    float xd1[4], xd2[4];
    {
        float4 a0 = *(const float4*)(xe);
        float4 a1 = *(const float4*)(xe + 4);
        float4 f0 = *(const float4*)(xf);
        float4 f1 = *(const float4*)(xf + 4);
#pragma unroll
        for (int g = 0; g < 4; g++) {
            xd1[g] = bsum[g] + dot8(a0, a1, wih[g]);
            xd2[g] = bsum[g] + dot8(f0, f1, wih[g]);
        }
    }

    float h0 = 0.f, h1r = 0.f, h2r = 0.f, h3r = 0.f;
    float ck = 0.f;

    for (int s2 = 0; s2 < 128; ++s2) {
        const float* nxe = xe + (s2 + 1) * 8;
        const float* nxf = xf + (s2 + 1) * 8;
        float4 na0 = *(const float4*)(nxe);
        float4 na1 = *(const float4*)(nxe + 4);
        float4 nf0 = *(const float4*)(nxf);
        float4 nf1 = *(const float4*)(nxf + 4);

        // ---- cell 1 ----
        float g0 = xd1[0] + h0 * whh[0][0] + h1r * whh[0][1] + h2r * whh[0][2] + h3r * whh[0][3];
        float g1 = xd1[1] + h0 * whh[1][0] + h1r * whh[1][1] + h2r * whh[1][2] + h3r * whh[1][3];
        float g2 = xd1[2] + h0 * whh[2][0] + h1r * whh[2][1] + h2r * whh[2][2] + h3r * whh[2][3];
        float g3 = xd1[3] + h0 * whh[3][0] + h1r * whh[3][1] + h2r * whh[3][2] + h3r * whh[3][3];
        float c1  = fsigmoid(g1) * ck + fsigmoid(g0) * ftanh(g2);
        float hk1 = fsigmoid(g3) * ftanh(c1);
        float b0 = qbcast<0>(hk1), b1 = qbcast<1>(hk1), b2 = qbcast<2>(hk1), b3 = qbcast<3>(hk1);
        float z = bpv + b0 * wpv[0] + b1 * wpv[1] + b2 * wpv[2] + b3 * wpv[3];
        if (k == 0) prog[b * 128 + s2] = fsigmoid(z);

        // ---- cell 2 ----
        float e0 = xd2[0] + b0 * whh[0][0] + b1 * whh[0][1] + b2 * whh[0][2] + b3 * whh[0][3];
        float e1 = xd2[1] + b0 * whh[1][0] + b1 * whh[1][1] + b2 * whh[1][2] + b3 * whh[1][3];
        float e2 = xd2[2] + b0 * whh[2][0] + b1 * whh[2][1] + b2 * whh[2][2] + b3 * whh[2][3];
        float e3 = xd2[3] + b0 * whh[3][0] + b1 * whh[3][1] + b2 * whh[3][2] + b3 * whh[3][3];
        float c2v = fsigmoid(e1) * c1 + fsigmoid(e0) * ftanh(e2);
        float hk2 = fsigmoid(e3) * ftanh(c2v);
        float d0 = qbcast<0>(hk2), d1 = qbcast<1>(hk2), d2 = qbcast<2>(hk2), d3 = qbcast<3>(hk2);
        float z2 = bpv + d0 * wpv[0] + d1 * wpv[1] + d2 * wpv[2] + d3 * wpv[3];
        if (k == 0) fprog[b * 128 + s2] = fsigmoid(z2);

        h0 = b0; h1r = b1; h2r = b2; h3r = b3; ck = c1;

#pragma unroll
        for (int g = 0; g < 4; g++) {
            xd1[g] = bsum[g] + dot8(na0, na1, wih[g]);
            xd2[g] = bsum[g] + dot8(nf0, nf1, wih[g]);
        }
    }
}

extern "C" void kernel_launch(void* const* d_in, const int* in_sizes, int n_in,
                              void* d_out, int out_size, void* d_ws, size_t ws_size,
                              hipStream_t stream) {
    const float* frames = (const float*)d_in[0];
    const float* Wf     = (const float*)d_in[1];
    const float* bf     = (const float*)d_in[2];
    const float* We     = (const float*)d_in[3];
    const float* be     = (const float*)d_in[4];
    const float* Wih    = (const float*)d_in[5];
    const float* Whh    = (const float*)d_in[6];
    const float* bih    = (const float*)d_in[7];
    const float* bhh    = (const float*)d_in[8];
    const float* Wp     = (const float*)d_in[9];
    const float* bp     = (const float*)d_in[10];

    float* out = (float*)d_out;
    float* out_prog   = out;                  // (16,128)
    float* out_fprog  = out + 2048;           // (16,128)
    float* out_pooled = out + 4096;           // (16,128,15)
    float* out_fc     = out + 4096 + 30720;   // (16,128,15)

    float* quad = (float*)d_ws;               // 6144*4 = 24576 floats

    spp_kernel<<<6144, 256, 0, stream>>>(frames, quad);
    size_t lds_bytes = (size_t)2 * 16 * BSTRIDE * sizeof(float);  // 132,608 B
    prep_lstm_kernel<<<1, 512, lds_bytes, stream>>>(quad, Wf, bf, We, be, Wih, Whh,
                                                    bih, bhh, Wp, bp, out_pooled,
                                                    out_fc, out_prog, out_fprog);
}